// Round 13
// baseline (253.864 us; speedup 1.0000x reference)
//
#include <hip/hip_runtime.h>

typedef unsigned short u16;
typedef unsigned int u32;

typedef __attribute__((ext_vector_type(8))) short bf16x8;
typedef __attribute__((ext_vector_type(4))) float f32x4;

#define QSCALE 0.18033688011112042f   // (1/8) * log2(e)

__device__ __forceinline__ u16 f2bf(float x) {
    union { float f; u32 u; } v; v.f = x;
    u32 r = (v.u + 0x7FFFu + ((v.u >> 16) & 1u)) >> 16;
    return (u16)r;
}
__device__ __forceinline__ float bf2f(u16 x) {
    union { u32 u; float f; } v; v.u = ((u32)x) << 16;
    return v.f;
}
// pack two f32 -> two bf16 (round-half-up) in one v_perm
__device__ __forceinline__ u32 pk2(float x, float y) {
    u32 ax = __float_as_uint(x) + 0x8000u;
    u32 ay = __float_as_uint(y) + 0x8000u;
    return __builtin_amdgcn_perm(ay, ax, 0x07060302u);
}

__device__ __forceinline__ void cp16(const u16* g, u16* l) {
    __builtin_amdgcn_global_load_lds(
        (__attribute__((address_space(1))) void*)(g),
        (__attribute__((address_space(3))) void*)(l), 16, 0, 0);
}

// ---------------- fused prep: hidden fp32->bf16 + 4 weight transposes ----------------
__global__ void k_prep(const float* __restrict__ hidden, u16* __restrict__ hA,
                       const float* __restrict__ Wq, u16* __restrict__ WqT,
                       const float* __restrict__ Wk, u16* __restrict__ WkT,
                       const float* __restrict__ Wv, u16* __restrict__ WvT,
                       const float* __restrict__ Wo, u16* __restrict__ WoT) {
    __shared__ u16 t[64][72];
    int bid = blockIdx.x, tid = threadIdx.x;
    if (bid < 4096) {
        int i = (bid * 256 + tid) * 8;
        float4 a = *(const float4*)(hidden + i);
        float4 b = *(const float4*)(hidden + i + 4);
        ushort4 o0; o0.x = f2bf(a.x); o0.y = f2bf(a.y); o0.z = f2bf(a.z); o0.w = f2bf(a.w);
        ushort4 o1; o1.x = f2bf(b.x); o1.y = f2bf(b.y); o1.z = f2bf(b.z); o1.w = f2bf(b.w);
        *(ushort4*)(hA + i) = o0;
        *(ushort4*)(hA + i + 4) = o1;
        return;
    }
    int rb = bid - 4096;
    const float* W; u16* Wt; int N, bx, by;
    if (rb < 256)      { W = Wq; Wt = WqT; N = 1024; bx = rb & 15; by = rb >> 4; }
    else if (rb < 320) { W = Wk; Wt = WkT; N = 256;  rb -= 256; bx = rb & 3; by = rb >> 2; }
    else if (rb < 384) { W = Wv; Wt = WvT; N = 256;  rb -= 320; bx = rb & 3; by = rb >> 2; }
    else               { W = Wo; Wt = WoT; N = 1024; rb -= 384; bx = rb & 15; by = rb >> 4; }
    const int K = 1024;
    int rr = tid >> 2;
    int cs = tid & 3;
    const float* src = W + (by*64 + rr)*N + bx*64 + cs*16;
#pragma unroll
    for (int j = 0; j < 16; j += 4) {
        float4 v = *(const float4*)(src + j);
        t[rr][cs*16 + j + 0] = f2bf(v.x);
        t[rr][cs*16 + j + 1] = f2bf(v.y);
        t[rr][cs*16 + j + 2] = f2bf(v.z);
        t[rr][cs*16 + j + 3] = f2bf(v.w);
    }
    __syncthreads();
    u16* dst = Wt + (bx*64 + rr)*K + by*64 + cs*16;
#pragma unroll
    for (int j = 0; j < 16; ++j) dst[j] = t[cs*16 + j][rr];
}

// ---------------- GEMM staging: A tile 128x32, B tile 64x32 into one buffer ----------------
__device__ __forceinline__ void stage_ab(const u16* __restrict__ Asrc, const u16* __restrict__ Bsrc,
                                         int kt, u16* buf, int tid, int wv) {
#pragma unroll
    for (int i = 0; i < 2; ++i) {
        int q = i*256 + tid;
        int r = q >> 2, sidx = q & 3;
        int s = sidx ^ ((r >> 1) & 3);
        cp16(Asrc + r*1024 + kt*32 + s*8, buf + i*2048 + wv*512);
    }
    {
        int r = tid >> 2, sidx = tid & 3;
        int s = sidx ^ ((r >> 1) & 3);
        cp16(Bsrc + r*1024 + kt*32 + s*8, buf + 4096 + wv*512);
    }
}

// ---------------- GEMM: 128x64 tiles. C = A[8192][1024] * Bt^T ----------------
// 4 waves x (32 rows x 64 cols); acc 8 f32x4. Each nb = one head for targets 0/1/2.
// target 2 (V) uses operand-swapped MFMA -> direct V^T store (32B s-contiguous chunks).
// LB(256,5): cap 102 VGPR to keep >=5 resident blocks at 24 KB LDS.
__global__ __launch_bounds__(256, 5) void k_gemm(
    const u16* __restrict__ A,
    const u16* __restrict__ Bq, const u16* __restrict__ Bk, const u16* __restrict__ Bv,
    float* __restrict__ outF,
    u16* __restrict__ outQ, u16* __restrict__ outK, u16* __restrict__ outVT,
    int mode)
{
    __shared__ __align__(16) u16 smem[12288];    // dbuf 2 x (A 4096 + B 2048)
    int tid = threadIdx.x;
    int lane = tid & 63, wv = tid >> 6;
    int l15 = lane & 15, quad = lane >> 4;
    int mb = blockIdx.x, nb = blockIdx.y;

    const u16* Bsrc; int target; int hh;
    if (mode == 0)    { Bsrc = Bq + nb*64*1024;      target = 3; hh = 0; }
    else if (nb < 16) { Bsrc = Bq + nb*64*1024;      target = 0; hh = nb; }
    else if (nb < 20) { Bsrc = Bk + (nb-16)*64*1024; target = 1; hh = nb-16; }
    else              { Bsrc = Bv + (nb-20)*64*1024; target = 2; hh = nb-20; }
    const u16* Asrc = A + mb*128*1024;
    bool swp = (target == 2);

    f32x4 zf = {0.f, 0.f, 0.f, 0.f};
    f32x4 acc[2][4];
#pragma unroll
    for (int i = 0; i < 2; ++i)
#pragma unroll
        for (int j = 0; j < 4; ++j) acc[i][j] = zf;

    stage_ab(Asrc, Bsrc, 0, smem, tid, wv);
    __syncthreads();

    for (int kt = 0; kt < 32; ++kt) {
        int cur = kt & 1;
        if (kt < 31) stage_ab(Asrc, Bsrc, kt + 1, smem + (cur^1)*6144, tid, wv);
        const u16* buf = smem + cur*6144;
        bf16x8 af[2], bfr[4];
#pragma unroll
        for (int mt = 0; mt < 2; ++mt) {
            int row = wv*32 + mt*16 + l15;
            int sidx = quad ^ ((row >> 1) & 3);
            af[mt] = *(const bf16x8*)(buf + row*32 + sidx*8);
        }
#pragma unroll
        for (int nt = 0; nt < 4; ++nt) {
            int row = nt*16 + l15;
            int sidx = quad ^ ((row >> 1) & 3);
            bfr[nt] = *(const bf16x8*)(buf + 4096 + row*32 + sidx*8);
        }
        if (swp) {
#pragma unroll
            for (int mt = 0; mt < 2; ++mt)
#pragma unroll
                for (int nt = 0; nt < 4; ++nt)
                    acc[mt][nt] = __builtin_amdgcn_mfma_f32_16x16x32_bf16(bfr[nt], af[mt], acc[mt][nt], 0, 0, 0);
        } else {
#pragma unroll
            for (int mt = 0; mt < 2; ++mt)
#pragma unroll
                for (int nt = 0; nt < 4; ++nt)
                    acc[mt][nt] = __builtin_amdgcn_mfma_f32_16x16x32_bf16(af[mt], bfr[nt], acc[mt][nt], 0, 0, 0);
        }
        __syncthreads();
    }

    if (target == 2) {
        // swapped: lane l15 = s-local, quad*4+rr = d-local
        int b = mb >> 4, s0 = (mb & 15) * 128;
#pragma unroll
        for (int mt = 0; mt < 2; ++mt) {
#pragma unroll
            for (int nt = 0; nt < 4; ++nt) {
#pragma unroll
                for (int rr = 0; rr < 4; ++rr) {
                    int s = s0 + wv*32 + mt*16 + l15;
                    int d = nt*16 + quad*4 + rr;
                    outVT[((b*4 + hh)*64 + d)*2048 + s] = f2bf(acc[mt][nt][rr]);
                }
            }
        }
        return;
    }

#pragma unroll
    for (int mt = 0; mt < 2; ++mt) {
#pragma unroll
        for (int nt = 0; nt < 4; ++nt) {
#pragma unroll
            for (int rr = 0; rr < 4; ++rr) {
                int row = mb*128 + wv*32 + mt*16 + quad*4 + rr;
                float v = acc[mt][nt][rr];
                if (target == 3) {
                    int cl = nb*64 + nt*16 + l15;
                    outF[row*1024 + cl] = v;
                } else {
                    int b = row >> 11, s = row & 2047;
                    int d = nt*16 + l15;
                    u16 bv = f2bf(v);
                    if (target == 0) outQ[((b*16 + hh)*2048 + s)*64 + d] = bv;
                    else             outK[((b*4  + hh)*2048 + s)*64 + d] = bv;
                }
            }
        }
    }
}

// ---------------- RMSNorm + RoPE in place on K only (32768 rows) ----------------
__global__ void k_knorm(u16* __restrict__ K,
                        const float* __restrict__ kw,
                        const float* __restrict__ cosp, const float* __restrict__ sinp)
{
    int row = blockIdx.x * 8 + (threadIdx.x >> 5);
    int tl = threadIdx.x & 31;
    u16* base = K + row*64;
    int s = row & 2047;
    u32 packed = *(const u32*)(base + 2*tl);
    float x0 = bf2f((u16)(packed & 0xffffu));
    float x1 = bf2f((u16)(packed >> 16));
    float ss = x0*x0 + x1*x1;
#pragma unroll
    for (int m = 1; m < 32; m <<= 1) ss += __shfl_xor(ss, m, 32);
    float inv = rsqrtf(ss * (1.0f/64.0f) + 1e-6f);
    float w0 = kw[2*tl], w1 = kw[2*tl+1];
    float c = cosp[s*64 + 2*tl], sn = sinp[s*64 + 2*tl];
    float xn0 = x0 * inv * w0, xn1 = x1 * inv * w1;
    float y0 = xn0*c - xn1*sn;
    float y1 = xn1*c + xn0*sn;
    *(u32*)(base + 2*tl) = pk2(y0, y1);
}

// ---------------- attention staging helper (64x64 K tile + 64x64 V^T tile) ----------------
__device__ __forceinline__ void stage_kv(const u16* __restrict__ Kg, const u16* __restrict__ Vg,
                                         int kt, u16* sK, u16* sV, int tid, int wv) {
#pragma unroll
    for (int i = 0; i < 2; ++i) {
        int q = i*256 + tid;
        int r = q >> 3, sidx = q & 7;
        int s = sidx ^ (r & 7);
        cp16(Kg + (kt*64 + r)*64 + s*8, sK + (i*256 + wv*64)*8);
        cp16(Vg + r*2048 + kt*64 + s*8, sV + (i*256 + wv*64)*8);
    }
}

// ---------------- flash attention: paired 64-row q-tiles, fused Q-norm, XCD-affinity ----------------
// S^T = K·Q^T; O^T = V^T·P^T; fixed-max softmax. Block handles q-tiles {31-p, p}:
// exactly 33 key-tiles, zero tail. XCD decode keeps each (b,hkv) KV set L2-resident.
// Tile-0 stage issued BEFORE the Q-norm prologue (DMA flies under the norm VALU);
// in-loop staging at loop bottom (R10-proven placement). NO cross-sub-tile prefetch
// (R11's failure); sub-tile 1's stage(0) comes after the epilogue's trailing barrier.
__global__ __launch_bounds__(256, 4) void k_attn(
    const u16* __restrict__ Q, const u16* __restrict__ K,
    const u16* __restrict__ VT, u16* __restrict__ attn,
    const float* __restrict__ qw,
    const float* __restrict__ cosp, const float* __restrict__ sinp)
{
    __shared__ __align__(16) u16 smemP[64*64];
    __shared__ __align__(16) u16 smemK[64*64];
    __shared__ __align__(16) u16 smemV[64*64];

    int tid = threadIdx.x;
    int lane = tid & 63, wv = tid >> 6;
    int l15 = lane & 15, quad = lane >> 4;

    // XCD-affinity decode: bid%8 + 8*((g>>3)*64 + hl*16 + p), g = b*4+hkv
    int bid = blockIdx.x;
    int r8 = bid & 7, q8 = bid >> 3;
    int g = ((q8 >> 6) << 3) | r8;      // 0..15
    int local = q8 & 63;
    int b = g >> 2, hkv = g & 3;
    int hl = local >> 4, p = local & 15;
    int h = hkv*4 + hl;

    const u16* Kg = K + ((b*4 + hkv)*2048)*64;
    const u16* Vg = VT + (b*4 + hkv)*64*2048;

    int qcol = wv*16 + l15;             // wave-local P row / q index

#pragma unroll
    for (int t = 0; t < 2; ++t) {
        int qi = t ? p : (31 - p);
        int q0 = qi * 64;
        const u16* Qg = Q + ((b*16 + h)*2048 + q0)*64;
        int qrow = q0 + qcol;

        // issue tile-0 K/V stage first: DMA overlaps the Q-norm VALU below
        stage_kv(Kg, Vg, 0, smemK, smemV, tid, wv);

        // ---- fused RMSNorm + RoPE + QSCALE on Q fragment (staging in flight) ----
        bf16x8 qf[2];
        {
            float xv[2][8];
            float ssum = 0.f;
#pragma unroll
            for (int ks = 0; ks < 2; ++ks) {
                bf16x8 raw = *(const bf16x8*)(Qg + qcol*64 + ks*32 + quad*8);
#pragma unroll
                for (int j = 0; j < 8; ++j) {
                    float x = bf2f((u16)raw[j]);
                    xv[ks][j] = x;
                    ssum += x*x;
                }
            }
            ssum += __shfl_xor(ssum, 16);
            ssum += __shfl_xor(ssum, 32);
            float inv = rsqrtf(ssum * (1.0f/64.0f) + 1e-6f);
#pragma unroll
            for (int ks = 0; ks < 2; ++ks) {
                int d0 = ks*32 + quad*8;
                float4 w0 = *(const float4*)(qw + d0);
                float4 w1 = *(const float4*)(qw + d0 + 4);
                float4 c0 = *(const float4*)(cosp + qrow*64 + d0);
                float4 c1 = *(const float4*)(cosp + qrow*64 + d0 + 4);
                float4 s0 = *(const float4*)(sinp + qrow*64 + d0);
                float4 s1 = *(const float4*)(sinp + qrow*64 + d0 + 4);
                float wa[8] = {w0.x,w0.y,w0.z,w0.w,w1.x,w1.y,w1.z,w1.w};
                float ca[8] = {c0.x,c0.y,c0.z,c0.w,c1.x,c1.y,c1.z,c1.w};
                float sa[8] = {s0.x,s0.y,s0.z,s0.w,s1.x,s1.y,s1.z,s1.w};
                union { u32 u[4]; bf16x8 v; } qq;
#pragma unroll
                for (int jj = 0; jj < 4; ++jj) {
                    float xe = xv[ks][2*jj]   * inv * wa[2*jj];
                    float xo = xv[ks][2*jj+1] * inv * wa[2*jj+1];
                    float ye = (xe*ca[2*jj]   - xo*sa[2*jj])   * QSCALE;
                    float yo = (xo*ca[2*jj+1] + xe*sa[2*jj+1]) * QSCALE;
                    qq.u[jj] = pk2(ye, yo);
                }
                qf[ks] = qq.v;
            }
        }

        f32x4 zf = {0.f, 0.f, 0.f, 0.f};
        f32x4 o[4];
#pragma unroll
        for (int mt = 0; mt < 4; ++mt) o[mt] = zf;
        float l_q = 0.f;

        for (int kt = 0; kt <= qi; ++kt) {
            __syncthreads();            // publish staged tile kt

            // ---- S^T = K·Q^T ----
            f32x4 sc[4];
#pragma unroll
            for (int mt = 0; mt < 4; ++mt) sc[mt] = zf;
#pragma unroll
            for (int ks = 0; ks < 2; ++ks) {
                bf16x8 kf[4];
#pragma unroll
                for (int mt = 0; mt < 4; ++mt) {
                    int row = mt*16 + l15;
                    int sidx = (ks*4 + quad) ^ (row & 7);
                    kf[mt] = *(const bf16x8*)(smemK + row*64 + sidx*8);
                }
#pragma unroll
                for (int mt = 0; mt < 4; ++mt)
                    sc[mt] = __builtin_amdgcn_mfma_f32_16x16x32_bf16(kf[mt], qf[ks], sc[mt], 0, 0, 0);
            }

            // ---- fixed-max softmax numerators, P^T to LDS ----
            if (kt == qi) {             // only the diagonal tile needs masking
                int keyb = kt*64 + quad*4;
#pragma unroll
                for (int mt = 0; mt < 4; ++mt)
#pragma unroll
                    for (int rr = 0; rr < 4; ++rr)
                        if (keyb + mt*16 + rr > qrow) sc[mt][rr] = -1e30f;
            }
            float rs = 0.f;
#pragma unroll
            for (int mt = 0; mt < 4; ++mt) {
                float p0 = __builtin_amdgcn_exp2f(sc[mt][0]);
                float p1 = __builtin_amdgcn_exp2f(sc[mt][1]);
                float p2 = __builtin_amdgcn_exp2f(sc[mt][2]);
                float p3 = __builtin_amdgcn_exp2f(sc[mt][3]);
                rs += (p0 + p1) + (p2 + p3);
                uint2 w; w.x = pk2(p0, p1); w.y = pk2(p2, p3);
                int gw = (mt*2 + (quad >> 1)) ^ (qcol & 7);
                *(uint2*)(smemP + qcol*64 + gw*8 + (quad & 1)*4) = w;
            }
            l_q += rs;

            // ---- O^T += V^T·P^T (wave-private P rows; in-order DS, no barrier) ----
#pragma unroll
            for (int ks2 = 0; ks2 < 2; ++ks2) {
                int gr = (ks2*4 + quad) ^ (qcol & 7);
                bf16x8 pf = *(const bf16x8*)(smemP + qcol*64 + gr*8);
                bf16x8 vf[4];
#pragma unroll
                for (int mt = 0; mt < 4; ++mt) {
                    int row = mt*16 + l15;
                    int sidx = (ks2*4 + quad) ^ (row & 7);
                    vf[mt] = *(const bf16x8*)(smemV + row*64 + sidx*8);
                }
#pragma unroll
                for (int mt = 0; mt < 4; ++mt)
                    o[mt] = __builtin_amdgcn_mfma_f32_16x16x32_bf16(vf[mt], pf, o[mt], 0, 0, 0);
            }
            __syncthreads();            // readers done; smemK/V safe to restage

            if (kt < qi) stage_kv(Kg, Vg, kt + 1, smemK, smemV, tid, wv);
        }

        // ---- epilogue: normalize, O^T -> LDS (swizzled) -> coalesced global ----
        float lt = l_q;
        lt += __shfl_xor(lt, 16);
        lt += __shfl_xor(lt, 32);
        float rl = 1.0f / lt;
#pragma unroll
        for (int mt = 0; mt < 4; ++mt) {
            uint2 w;
            w.x = pk2(o[mt][0]*rl, o[mt][1]*rl);
            w.y = pk2(o[mt][2]*rl, o[mt][3]*rl);
            int gw = (mt*2 + (quad >> 1)) ^ (qcol & 7);
            *(uint2*)(smemP + qcol*64 + gw*8 + (quad & 1)*4) = w;
        }
        __syncthreads();
        {
            int r2 = tid >> 2, c = tid & 3;
            u16* dst = attn + (b*2048 + q0 + r2)*1024 + h*64 + c*16;
            int g0 = (c*2) ^ (r2 & 7);
            int g1 = (c*2 + 1) ^ (r2 & 7);
            *(uint4*)(dst)     = *(const uint4*)(smemP + r2*64 + g0*8);
            *(uint4*)(dst + 8) = *(const uint4*)(smemP + r2*64 + g1*8);
        }
        __syncthreads();   // protect smemP/smemK/smemV before next sub-tile
    }
}

extern "C" void kernel_launch(void* const* d_in, const int* in_sizes, int n_in,
                              void* d_out, int out_size, void* d_ws, size_t ws_size,
                              hipStream_t stream) {
    const float* hidden = (const float*)d_in[0];
    // d_in[1] = causal_mask (reconstructed analytically, unused)
    const float* cosp = (const float*)d_in[2];
    const float* sinp = (const float*)d_in[3];
    const float* Wq = (const float*)d_in[4];
    const float* Wk = (const float*)d_in[5];
    const float* Wv = (const float*)d_in[6];
    const float* Wo = (const float*)d_in[7];
    const float* qw = (const float*)d_in[8];
    const float* kw = (const float*)d_in[9];
    float* out = (float*)d_out;

    char* ws = (char*)d_ws;
    u16* hA   = (u16*)(ws);                 // 16 MB  hidden bf16; reused as attn buffer later
    u16* WqT  = (u16*)(ws + 16777216);      // 2 MB
    u16* WkT  = (u16*)(ws + 18874368);      // 0.5 MB
    u16* WvT  = (u16*)(ws + 19398656);      // 0.5 MB
    u16* WoT  = (u16*)(ws + 19922944);      // 2 MB
    u16* Qws  = (u16*)(ws + 22020096);      // 16 MB (raw q; normed on the fly in k_attn)
    u16* Kws  = (u16*)(ws + 38797312);      // 4 MB
    u16* VTw  = (u16*)(ws + 42991616);      // 4 MB   -> total 47.2 MB
    u16* attn = hA;                         // alias: hA dead after QKV GEMM

    k_prep<<<4736, 256, 0, stream>>>(hidden, hA, Wq, WqT, Wk, WkT, Wv, WvT, Wo, WoT);
    k_gemm<<<dim3(64, 24), 256, 0, stream>>>(hA, WqT, WkT, WvT, nullptr, Qws, Kws, VTw, 1);
    k_knorm<<<4096, 256, 0, stream>>>(Kws, kw, cosp, sinp);
    k_attn<<<1024, 256, 0, stream>>>(Qws, Kws, VTw, attn, qw, cosp, sinp);
    k_gemm<<<dim3(64, 16), 256, 0, stream>>>(attn, WoT, nullptr, nullptr, out, nullptr, nullptr, nullptr, 0);
}

// Round 14
// 240.360 us; speedup vs baseline: 1.0562x; 1.0562x over previous
//
#include <hip/hip_runtime.h>

typedef unsigned short u16;
typedef unsigned int u32;

typedef __attribute__((ext_vector_type(8))) short bf16x8;
typedef __attribute__((ext_vector_type(4))) float f32x4;

#define QSCALE 0.18033688011112042f   // (1/8) * log2(e)

__device__ __forceinline__ u16 f2bf(float x) {
    union { float f; u32 u; } v; v.f = x;
    u32 r = (v.u + 0x7FFFu + ((v.u >> 16) & 1u)) >> 16;
    return (u16)r;
}
__device__ __forceinline__ float bf2f(u16 x) {
    union { u32 u; float f; } v; v.u = ((u32)x) << 16;
    return v.f;
}
// pack two f32 -> two bf16 (round-half-up) in one v_perm
__device__ __forceinline__ u32 pk2(float x, float y) {
    u32 ax = __float_as_uint(x) + 0x8000u;
    u32 ay = __float_as_uint(y) + 0x8000u;
    return __builtin_amdgcn_perm(ay, ax, 0x07060302u);
}

__device__ __forceinline__ void cp16(const u16* g, u16* l) {
    __builtin_amdgcn_global_load_lds(
        (__attribute__((address_space(1))) void*)(g),
        (__attribute__((address_space(3))) void*)(l), 16, 0, 0);
}

// ---------------- fused prep: hidden fp32->bf16 + 4 weight transposes ----------------
__global__ void k_prep(const float* __restrict__ hidden, u16* __restrict__ hA,
                       const float* __restrict__ Wq, u16* __restrict__ WqT,
                       const float* __restrict__ Wk, u16* __restrict__ WkT,
                       const float* __restrict__ Wv, u16* __restrict__ WvT,
                       const float* __restrict__ Wo, u16* __restrict__ WoT) {
    __shared__ u16 t[64][72];
    int bid = blockIdx.x, tid = threadIdx.x;
    if (bid < 4096) {
        int i = (bid * 256 + tid) * 8;
        float4 a = *(const float4*)(hidden + i);
        float4 b = *(const float4*)(hidden + i + 4);
        ushort4 o0; o0.x = f2bf(a.x); o0.y = f2bf(a.y); o0.z = f2bf(a.z); o0.w = f2bf(a.w);
        ushort4 o1; o1.x = f2bf(b.x); o1.y = f2bf(b.y); o1.z = f2bf(b.z); o1.w = f2bf(b.w);
        *(ushort4*)(hA + i) = o0;
        *(ushort4*)(hA + i + 4) = o1;
        return;
    }
    int rb = bid - 4096;
    const float* W; u16* Wt; int N, bx, by;
    if (rb < 256)      { W = Wq; Wt = WqT; N = 1024; bx = rb & 15; by = rb >> 4; }
    else if (rb < 320) { W = Wk; Wt = WkT; N = 256;  rb -= 256; bx = rb & 3; by = rb >> 2; }
    else if (rb < 384) { W = Wv; Wt = WvT; N = 256;  rb -= 320; bx = rb & 3; by = rb >> 2; }
    else               { W = Wo; Wt = WoT; N = 1024; rb -= 384; bx = rb & 15; by = rb >> 4; }
    const int K = 1024;
    int rr = tid >> 2;
    int cs = tid & 3;
    const float* src = W + (by*64 + rr)*N + bx*64 + cs*16;
#pragma unroll
    for (int j = 0; j < 16; j += 4) {
        float4 v = *(const float4*)(src + j);
        t[rr][cs*16 + j + 0] = f2bf(v.x);
        t[rr][cs*16 + j + 1] = f2bf(v.y);
        t[rr][cs*16 + j + 2] = f2bf(v.z);
        t[rr][cs*16 + j + 3] = f2bf(v.w);
    }
    __syncthreads();
    u16* dst = Wt + (bx*64 + rr)*K + by*64 + cs*16;
#pragma unroll
    for (int j = 0; j < 16; ++j) dst[j] = t[cs*16 + j][rr];
}

// ---------------- GEMM staging: A tile 128x32, B tile 64x32 into one buffer ----------------
__device__ __forceinline__ void stage_ab(const u16* __restrict__ Asrc, const u16* __restrict__ Bsrc,
                                         int kt, u16* buf, int tid, int wv) {
#pragma unroll
    for (int i = 0; i < 2; ++i) {
        int q = i*256 + tid;
        int r = q >> 2, sidx = q & 3;
        int s = sidx ^ ((r >> 1) & 3);
        cp16(Asrc + r*1024 + kt*32 + s*8, buf + i*2048 + wv*512);
    }
    {
        int r = tid >> 2, sidx = tid & 3;
        int s = sidx ^ ((r >> 1) & 3);
        cp16(Bsrc + r*1024 + kt*32 + s*8, buf + 4096 + wv*512);
    }
}

// ---------------- GEMM: 128x64 tiles. C = A[8192][1024] * Bt^T ----------------
// 4 waves x (32 rows x 64 cols); acc 8 f32x4. Each nb = one head for targets 0/1/2.
// target 2 (V) uses operand-swapped MFMA -> direct V^T store. No launch bound
// (R13's LB(256,5) cap regressed ~13 us — compiler's natural allocation wins).
__global__ __launch_bounds__(256) void k_gemm(
    const u16* __restrict__ A,
    const u16* __restrict__ Bq, const u16* __restrict__ Bk, const u16* __restrict__ Bv,
    float* __restrict__ outF,
    u16* __restrict__ outQ, u16* __restrict__ outK, u16* __restrict__ outVT,
    int mode)
{
    __shared__ __align__(16) u16 smem[12288];    // dbuf 2 x (A 4096 + B 2048)
    int tid = threadIdx.x;
    int lane = tid & 63, wv = tid >> 6;
    int l15 = lane & 15, quad = lane >> 4;
    int mb = blockIdx.x, nb = blockIdx.y;

    const u16* Bsrc; int target; int hh;
    if (mode == 0)    { Bsrc = Bq + nb*64*1024;      target = 3; hh = 0; }
    else if (nb < 16) { Bsrc = Bq + nb*64*1024;      target = 0; hh = nb; }
    else if (nb < 20) { Bsrc = Bk + (nb-16)*64*1024; target = 1; hh = nb-16; }
    else              { Bsrc = Bv + (nb-20)*64*1024; target = 2; hh = nb-20; }
    const u16* Asrc = A + mb*128*1024;
    bool swp = (target == 2);

    f32x4 zf = {0.f, 0.f, 0.f, 0.f};
    f32x4 acc[2][4];
#pragma unroll
    for (int i = 0; i < 2; ++i)
#pragma unroll
        for (int j = 0; j < 4; ++j) acc[i][j] = zf;

    stage_ab(Asrc, Bsrc, 0, smem, tid, wv);
    __syncthreads();

    for (int kt = 0; kt < 32; ++kt) {
        int cur = kt & 1;
        if (kt < 31) stage_ab(Asrc, Bsrc, kt + 1, smem + (cur^1)*6144, tid, wv);
        const u16* buf = smem + cur*6144;
        bf16x8 af[2], bfr[4];
#pragma unroll
        for (int mt = 0; mt < 2; ++mt) {
            int row = wv*32 + mt*16 + l15;
            int sidx = quad ^ ((row >> 1) & 3);
            af[mt] = *(const bf16x8*)(buf + row*32 + sidx*8);
        }
#pragma unroll
        for (int nt = 0; nt < 4; ++nt) {
            int row = nt*16 + l15;
            int sidx = quad ^ ((row >> 1) & 3);
            bfr[nt] = *(const bf16x8*)(buf + 4096 + row*32 + sidx*8);
        }
        if (swp) {
#pragma unroll
            for (int mt = 0; mt < 2; ++mt)
#pragma unroll
                for (int nt = 0; nt < 4; ++nt)
                    acc[mt][nt] = __builtin_amdgcn_mfma_f32_16x16x32_bf16(bfr[nt], af[mt], acc[mt][nt], 0, 0, 0);
        } else {
#pragma unroll
            for (int mt = 0; mt < 2; ++mt)
#pragma unroll
                for (int nt = 0; nt < 4; ++nt)
                    acc[mt][nt] = __builtin_amdgcn_mfma_f32_16x16x32_bf16(af[mt], bfr[nt], acc[mt][nt], 0, 0, 0);
        }
        __syncthreads();
    }

    if (target == 2) {
        // swapped: lane l15 = s-local, quad*4+rr = d-local
        int b = mb >> 4, s0 = (mb & 15) * 128;
#pragma unroll
        for (int mt = 0; mt < 2; ++mt) {
#pragma unroll
            for (int nt = 0; nt < 4; ++nt) {
#pragma unroll
                for (int rr = 0; rr < 4; ++rr) {
                    int s = s0 + wv*32 + mt*16 + l15;
                    int d = nt*16 + quad*4 + rr;
                    outVT[((b*4 + hh)*64 + d)*2048 + s] = f2bf(acc[mt][nt][rr]);
                }
            }
        }
        return;
    }

#pragma unroll
    for (int mt = 0; mt < 2; ++mt) {
#pragma unroll
        for (int nt = 0; nt < 4; ++nt) {
#pragma unroll
            for (int rr = 0; rr < 4; ++rr) {
                int row = mb*128 + wv*32 + mt*16 + quad*4 + rr;
                float v = acc[mt][nt][rr];
                if (target == 3) {
                    int cl = nb*64 + nt*16 + l15;
                    outF[row*1024 + cl] = v;
                } else {
                    int b = row >> 11, s = row & 2047;
                    int d = nt*16 + l15;
                    u16 bv = f2bf(v);
                    if (target == 0) outQ[((b*16 + hh)*2048 + s)*64 + d] = bv;
                    else             outK[((b*4  + hh)*2048 + s)*64 + d] = bv;
                }
            }
        }
    }
}

// ---------------- RMSNorm + RoPE in place on K only (32768 rows) ----------------
__global__ void k_knorm(u16* __restrict__ K,
                        const float* __restrict__ kw,
                        const float* __restrict__ cosp, const float* __restrict__ sinp)
{
    int row = blockIdx.x * 8 + (threadIdx.x >> 5);
    int tl = threadIdx.x & 31;
    u16* base = K + row*64;
    int s = row & 2047;
    u32 packed = *(const u32*)(base + 2*tl);
    float x0 = bf2f((u16)(packed & 0xffffu));
    float x1 = bf2f((u16)(packed >> 16));
    float ss = x0*x0 + x1*x1;
#pragma unroll
    for (int m = 1; m < 32; m <<= 1) ss += __shfl_xor(ss, m, 32);
    float inv = rsqrtf(ss * (1.0f/64.0f) + 1e-6f);
    float w0 = kw[2*tl], w1 = kw[2*tl+1];
    float c = cosp[s*64 + 2*tl], sn = sinp[s*64 + 2*tl];
    float xn0 = x0 * inv * w0, xn1 = x1 * inv * w1;
    float y0 = xn0*c - xn1*sn;
    float y1 = xn1*c + xn0*sn;
    *(u32*)(base + 2*tl) = pk2(y0, y1);
}

// ---------------- attention staging helper (64x64 K tile + 64x64 V^T tile) ----------------
__device__ __forceinline__ void stage_kv(const u16* __restrict__ Kg, const u16* __restrict__ Vg,
                                         int kt, u16* sK, u16* sV, int tid, int wv) {
#pragma unroll
    for (int i = 0; i < 2; ++i) {
        int q = i*256 + tid;
        int r = q >> 3, sidx = q & 7;
        int s = sidx ^ (r & 7);
        cp16(Kg + (kt*64 + r)*64 + s*8, sK + (i*256 + wv*64)*8);
        cp16(Vg + r*2048 + kt*64 + s*8, sV + (i*256 + wv*64)*8);
    }
}

// ---------------- flash attention: paired 64-row q-tiles, fused Q-norm, XCD-affinity ----------------
// S^T = K·Q^T; O^T = V^T·P^T; fixed-max softmax. Block handles q-tiles {31-p, p}:
// exactly 33 key-tiles, zero tail. XCD decode keeps each (b,hkv) KV set L2-resident.
// Tile-0 stage issued BEFORE the Q-norm prologue (DMA under norm VALU — R13: -2.5 us);
// in-loop staging at loop bottom. NO cross-sub-tile prefetch (R11's failure).
__global__ __launch_bounds__(256, 4) void k_attn(
    const u16* __restrict__ Q, const u16* __restrict__ K,
    const u16* __restrict__ VT, u16* __restrict__ attn,
    const float* __restrict__ qw,
    const float* __restrict__ cosp, const float* __restrict__ sinp)
{
    __shared__ __align__(16) u16 smemP[64*64];
    __shared__ __align__(16) u16 smemK[64*64];
    __shared__ __align__(16) u16 smemV[64*64];

    int tid = threadIdx.x;
    int lane = tid & 63, wv = tid >> 6;
    int l15 = lane & 15, quad = lane >> 4;

    // XCD-affinity decode: bid%8 + 8*((g>>3)*64 + hl*16 + p), g = b*4+hkv
    int bid = blockIdx.x;
    int r8 = bid & 7, q8 = bid >> 3;
    int g = ((q8 >> 6) << 3) | r8;      // 0..15
    int local = q8 & 63;
    int b = g >> 2, hkv = g & 3;
    int hl = local >> 4, p = local & 15;
    int h = hkv*4 + hl;

    const u16* Kg = K + ((b*4 + hkv)*2048)*64;
    const u16* Vg = VT + (b*4 + hkv)*64*2048;

    int qcol = wv*16 + l15;             // wave-local P row / q index

#pragma unroll
    for (int t = 0; t < 2; ++t) {
        int qi = t ? p : (31 - p);
        int q0 = qi * 64;
        const u16* Qg = Q + ((b*16 + h)*2048 + q0)*64;
        int qrow = q0 + qcol;

        // issue tile-0 K/V stage first: DMA overlaps the Q-norm VALU below
        stage_kv(Kg, Vg, 0, smemK, smemV, tid, wv);

        // ---- fused RMSNorm + RoPE + QSCALE on Q fragment (staging in flight) ----
        bf16x8 qf[2];
        {
            float xv[2][8];
            float ssum = 0.f;
#pragma unroll
            for (int ks = 0; ks < 2; ++ks) {
                bf16x8 raw = *(const bf16x8*)(Qg + qcol*64 + ks*32 + quad*8);
#pragma unroll
                for (int j = 0; j < 8; ++j) {
                    float x = bf2f((u16)raw[j]);
                    xv[ks][j] = x;
                    ssum += x*x;
                }
            }
            ssum += __shfl_xor(ssum, 16);
            ssum += __shfl_xor(ssum, 32);
            float inv = rsqrtf(ssum * (1.0f/64.0f) + 1e-6f);
#pragma unroll
            for (int ks = 0; ks < 2; ++ks) {
                int d0 = ks*32 + quad*8;
                float4 w0 = *(const float4*)(qw + d0);
                float4 w1 = *(const float4*)(qw + d0 + 4);
                float4 c0 = *(const float4*)(cosp + qrow*64 + d0);
                float4 c1 = *(const float4*)(cosp + qrow*64 + d0 + 4);
                float4 s0 = *(const float4*)(sinp + qrow*64 + d0);
                float4 s1 = *(const float4*)(sinp + qrow*64 + d0 + 4);
                float wa[8] = {w0.x,w0.y,w0.z,w0.w,w1.x,w1.y,w1.z,w1.w};
                float ca[8] = {c0.x,c0.y,c0.z,c0.w,c1.x,c1.y,c1.z,c1.w};
                float sa[8] = {s0.x,s0.y,s0.z,s0.w,s1.x,s1.y,s1.z,s1.w};
                union { u32 u[4]; bf16x8 v; } qq;
#pragma unroll
                for (int jj = 0; jj < 4; ++jj) {
                    float xe = xv[ks][2*jj]   * inv * wa[2*jj];
                    float xo = xv[ks][2*jj+1] * inv * wa[2*jj+1];
                    float ye = (xe*ca[2*jj]   - xo*sa[2*jj])   * QSCALE;
                    float yo = (xo*ca[2*jj+1] + xe*sa[2*jj+1]) * QSCALE;
                    qq.u[jj] = pk2(ye, yo);
                }
                qf[ks] = qq.v;
            }
        }

        f32x4 zf = {0.f, 0.f, 0.f, 0.f};
        f32x4 o[4];
#pragma unroll
        for (int mt = 0; mt < 4; ++mt) o[mt] = zf;
        float l_q = 0.f;

        for (int kt = 0; kt <= qi; ++kt) {
            __syncthreads();            // publish staged tile kt

            // ---- S^T = K·Q^T ----
            f32x4 sc[4];
#pragma unroll
            for (int mt = 0; mt < 4; ++mt) sc[mt] = zf;
#pragma unroll
            for (int ks = 0; ks < 2; ++ks) {
                bf16x8 kf[4];
#pragma unroll
                for (int mt = 0; mt < 4; ++mt) {
                    int row = mt*16 + l15;
                    int sidx = (ks*4 + quad) ^ (row & 7);
                    kf[mt] = *(const bf16x8*)(smemK + row*64 + sidx*8);
                }
#pragma unroll
                for (int mt = 0; mt < 4; ++mt)
                    sc[mt] = __builtin_amdgcn_mfma_f32_16x16x32_bf16(kf[mt], qf[ks], sc[mt], 0, 0, 0);
            }

            // ---- fixed-max softmax numerators, P^T to LDS ----
            if (kt == qi) {             // only the diagonal tile needs masking
                int keyb = kt*64 + quad*4;
#pragma unroll
                for (int mt = 0; mt < 4; ++mt)
#pragma unroll
                    for (int rr = 0; rr < 4; ++rr)
                        if (keyb + mt*16 + rr > qrow) sc[mt][rr] = -1e30f;
            }
            float rs = 0.f;
#pragma unroll
            for (int mt = 0; mt < 4; ++mt) {
                float p0 = __builtin_amdgcn_exp2f(sc[mt][0]);
                float p1 = __builtin_amdgcn_exp2f(sc[mt][1]);
                float p2 = __builtin_amdgcn_exp2f(sc[mt][2]);
                float p3 = __builtin_amdgcn_exp2f(sc[mt][3]);
                rs += (p0 + p1) + (p2 + p3);
                uint2 w; w.x = pk2(p0, p1); w.y = pk2(p2, p3);
                int gw = (mt*2 + (quad >> 1)) ^ (qcol & 7);
                *(uint2*)(smemP + qcol*64 + gw*8 + (quad & 1)*4) = w;
            }
            l_q += rs;

            // ---- O^T += V^T·P^T (wave-private P rows; in-order DS, no barrier) ----
#pragma unroll
            for (int ks2 = 0; ks2 < 2; ++ks2) {
                int gr = (ks2*4 + quad) ^ (qcol & 7);
                bf16x8 pf = *(const bf16x8*)(smemP + qcol*64 + gr*8);
                bf16x8 vf[4];
#pragma unroll
                for (int mt = 0; mt < 4; ++mt) {
                    int row = mt*16 + l15;
                    int sidx = (ks2*4 + quad) ^ (row & 7);
                    vf[mt] = *(const bf16x8*)(smemV + row*64 + sidx*8);
                }
#pragma unroll
                for (int mt = 0; mt < 4; ++mt)
                    o[mt] = __builtin_amdgcn_mfma_f32_16x16x32_bf16(vf[mt], pf, o[mt], 0, 0, 0);
            }
            __syncthreads();            // readers done; smemK/V safe to restage

            if (kt < qi) stage_kv(Kg, Vg, kt + 1, smemK, smemV, tid, wv);
        }

        // ---- epilogue: normalize, O^T -> LDS (swizzled) -> coalesced global ----
        float lt = l_q;
        lt += __shfl_xor(lt, 16);
        lt += __shfl_xor(lt, 32);
        float rl = 1.0f / lt;
#pragma unroll
        for (int mt = 0; mt < 4; ++mt) {
            uint2 w;
            w.x = pk2(o[mt][0]*rl, o[mt][1]*rl);
            w.y = pk2(o[mt][2]*rl, o[mt][3]*rl);
            int gw = (mt*2 + (quad >> 1)) ^ (qcol & 7);
            *(uint2*)(smemP + qcol*64 + gw*8 + (quad & 1)*4) = w;
        }
        __syncthreads();
        {
            int r2 = tid >> 2, c = tid & 3;
            u16* dst = attn + (b*2048 + q0 + r2)*1024 + h*64 + c*16;
            int g0 = (c*2) ^ (r2 & 7);
            int g1 = (c*2 + 1) ^ (r2 & 7);
            *(uint4*)(dst)     = *(const uint4*)(smemP + r2*64 + g0*8);
            *(uint4*)(dst + 8) = *(const uint4*)(smemP + r2*64 + g1*8);
        }
        __syncthreads();   // protect smemP/smemK/smemV before next sub-tile
    }
}

extern "C" void kernel_launch(void* const* d_in, const int* in_sizes, int n_in,
                              void* d_out, int out_size, void* d_ws, size_t ws_size,
                              hipStream_t stream) {
    const float* hidden = (const float*)d_in[0];
    // d_in[1] = causal_mask (reconstructed analytically, unused)
    const float* cosp = (const float*)d_in[2];
    const float* sinp = (const float*)d_in[3];
    const float* Wq = (const float*)d_in[4];
    const float* Wk = (const float*)d_in[5];
    const float* Wv = (const float*)d_in[6];
    const float* Wo = (const float*)d_in[7];
    const float* qw = (const float*)d_in[8];
    const float* kw = (const float*)d_in[9];
    float* out = (float*)d_out;

    char* ws = (char*)d_ws;
    u16* hA   = (u16*)(ws);                 // 16 MB  hidden bf16; reused as attn buffer later
    u16* WqT  = (u16*)(ws + 16777216);      // 2 MB
    u16* WkT  = (u16*)(ws + 18874368);      // 0.5 MB
    u16* WvT  = (u16*)(ws + 19398656);      // 0.5 MB
    u16* WoT  = (u16*)(ws + 19922944);      // 2 MB
    u16* Qws  = (u16*)(ws + 22020096);      // 16 MB (raw q; normed on the fly in k_attn)
    u16* Kws  = (u16*)(ws + 38797312);      // 4 MB
    u16* VTw  = (u16*)(ws + 42991616);      // 4 MB   -> total 47.2 MB
    u16* attn = hA;                         // alias: hA dead after QKV GEMM

    k_prep<<<4736, 256, 0, stream>>>(hidden, hA, Wq, WqT, Wk, WkT, Wv, WvT, Wo, WoT);
    k_gemm<<<dim3(64, 24), 256, 0, stream>>>(hA, WqT, WkT, WvT, nullptr, Qws, Kws, VTw, 1);
    k_knorm<<<4096, 256, 0, stream>>>(Kws, kw, cosp, sinp);
    k_attn<<<1024, 256, 0, stream>>>(Qws, Kws, VTw, attn, qw, cosp, sinp);
    k_gemm<<<dim3(64, 16), 256, 0, stream>>>(attn, WoT, nullptr, nullptr, out, nullptr, nullptr, nullptr, 0);
}